// Round 1
// 6245.871 us; speedup vs baseline: 1.5240x; 1.5240x over previous
//
#include <hip/hip_runtime.h>
#include <hip/hip_bf16.h>

// ---------------- problem constants ----------------
#define TT 70
#define BB 80
#define TB (TT*BB)          // 5600
#define TBP 5632            // padded to 128-multiple for M tiles
#define EE 400
#define EP 416              // K padded to 32-mult
#define H1 1150
#define HP1 1152
#define H2r 400
#define HP2 512             // padded to 128-mult so the 4-way k-split divides evenly
#define G1 4600             // 4*H1
#define G1P 4608
#define G2 1600
#define G2P 1664
#define VV 33278
#define VP 33280

typedef short bf16x8 __attribute__((ext_vector_type(8)));
typedef float floatx4 __attribute__((ext_vector_type(4)));
using bf16 = __hip_bfloat16;

__device__ inline void async_load16(const void* g, void* lds) {
  __builtin_amdgcn_global_load_lds(
      (const __attribute__((address_space(1))) void*)g,
      (__attribute__((address_space(3))) void*)lds,
      16, 0, 0);
}

// ---------------- fp32 -> bf16 convert with zero padding ----------------
__global__ void conv_pad(const float* __restrict__ src, bf16* __restrict__ dst,
                         int N, int K, int Npad, int Kpad) {
  long long idx = (long long)blockIdx.x * blockDim.x + threadIdx.x;
  long long total = (long long)Npad * Kpad;
  if (idx >= total) return;
  int row = (int)(idx / Kpad), col = (int)(idx % Kpad);
  float v = (row < N && col < K) ? src[(long long)row * K + col] : 0.f;
  dst[idx] = __float2bfloat16(v);
}

// c-state init (fp32 copy with pad stride)
__global__ void cinit(const float* __restrict__ c0, float* __restrict__ c, int H, int Hp) {
  int idx = blockIdx.x * blockDim.x + threadIdx.x;
  if (idx >= BB * Hp) return;
  int b = idx / Hp, j = idx % Hp;
  c[idx] = (j < H) ? c0[b * H + j] : 0.f;
}

// zero-fill (16B granules) — used to clear y2's pad columns once per launch
__global__ void zfill16(void* p, long long n16) {
  long long i = (long long)blockIdx.x * blockDim.x + threadIdx.x;
  if (i < n16) ((int4*)p)[i] = make_int4(0, 0, 0, 0);
}

// ---------------- embedding gather -> bf16 [TB, EP] ----------------
__global__ void emb_gather(const int* __restrict__ tokens, const float* __restrict__ embW,
                           bf16* __restrict__ x0) {
  int row = blockIdx.x;                       // 0..5599
  int tok = tokens[row];
  const float* src = embW + (long long)tok * EE;
  for (int col = threadIdx.x; col < EP; col += blockDim.x)
    x0[(long long)row * EP + col] = __float2bfloat16(col < EE ? src[col] : 0.f);
}

// ---------------- bf16 NT GEMM: C[M,N] = A[M,K]*B[N,K]^T (+bias1+bias2) ----------------
// A row-major lda=K(pad), B row-major ldb=K(pad), C fp32 row-major ldc.
// Block = 256 threads (4 waves), tile 128x128, BK=32; m97-style global_load_lds staging.
// ntc=1 -> non-temporal C stores (decoder: keep streaming 745MB write out of L3 so B stays resident)
__global__ __launch_bounds__(256) void gemm_bf16_nt(
    const bf16* __restrict__ A, int lda,
    const bf16* __restrict__ B, int ldb,
    float* __restrict__ C, long long ldc,
    int Mreal, int Nreal, int K,
    const float* __restrict__ bias1, const float* __restrict__ bias2,
    int ntc) {
  __shared__ bf16 As[128][32];
  __shared__ bf16 Bs[128][32];
  const int tid = threadIdx.x;
  const int wave = tid >> 6, lane = tid & 63;
  const int tm = blockIdx.y * 128, tn = blockIdx.x * 128;
  const int wm = (wave & 1) * 64, wn = (wave >> 1) * 64;
  const int lr = lane & 15, lk = (lane >> 4) * 8;

  floatx4 acc[4][4] = {};

  for (int k0 = 0; k0 < K; k0 += 32) {
    __syncthreads();
#pragma unroll
    for (int q = 0; q < 2; ++q) {
      int idx = q * 256 + tid;
      int row = idx >> 2, col = (idx & 3) * 8;
      async_load16(A + (long long)(tm + row) * lda + k0 + col,
                   (char*)&As[0][0] + q * 4096 + wave * 1024);
      async_load16(B + (long long)(tn + row) * ldb + k0 + col,
                   (char*)&Bs[0][0] + q * 4096 + wave * 1024);
    }
    asm volatile("s_waitcnt vmcnt(0)" ::: "memory");
    __syncthreads();
    bf16x8 af[4], bfr[4];
#pragma unroll
    for (int mi = 0; mi < 4; ++mi) af[mi] = *(const bf16x8*)&As[wm + mi * 16 + lr][lk];
#pragma unroll
    for (int ni = 0; ni < 4; ++ni) bfr[ni] = *(const bf16x8*)&Bs[wn + ni * 16 + lr][lk];
#pragma unroll
    for (int mi = 0; mi < 4; ++mi)
#pragma unroll
      for (int ni = 0; ni < 4; ++ni)
        acc[mi][ni] = __builtin_amdgcn_mfma_f32_16x16x32_bf16(af[mi], bfr[ni], acc[mi][ni], 0, 0, 0);
  }

  const int rb = (lane >> 4) * 4;
#pragma unroll
  for (int ni = 0; ni < 4; ++ni) {
    int col = tn + wn + ni * 16 + lr;
    if (col >= Nreal) continue;
    float badd = (bias1 ? bias1[col] : 0.f) + (bias2 ? bias2[col] : 0.f);
#pragma unroll
    for (int mi = 0; mi < 4; ++mi)
#pragma unroll
      for (int i = 0; i < 4; ++i) {
        int row = tm + wm + mi * 16 + rb + i;
        if (row < Mreal) {
          float v = acc[mi][ni][i] + badd;
          if (ntc) __builtin_nontemporal_store(v, &C[(long long)row * ldc + col]);
          else C[(long long)row * ldc + col] = v;
        }
      }
  }
}

// ---------------- fused LSTM step (k-split, 1024 threads) ----------------
// grid.x blocks, each owns 16 h-columns (j0=blockIdx.x*16).
// 16 waves: wave = (kw<<2)|g ; gate g in [0,4), k-slice kw in [0,4).
// Wave (g,kw) computes partial gates[b, g*H + j0..j0+15] over k in {kw*32 + ki*128}.
// Partials summed in LDS; elementwise epilogue in fp32; writes y[t] bf16 (+ hT/cT on last step).
// HP is compile-time so the k-loop (HP/128 iters) fully unrolls and pipelines.
template<int HP>
__global__ __launch_bounds__(1024) void lstm_step(
    const bf16* __restrict__ hprev,   // [80, HP]
    const bf16* __restrict__ Whh,     // [4H(+pad rows), HP] bf16
    const float* __restrict__ xWt,    // [80, ldxw] (this t's slice, biases prefolded)
    int ldxw,
    float* __restrict__ c,            // [80, HP]
    bf16* __restrict__ yt,            // [80, HP]
    int H,
    float* __restrict__ hT, float* __restrict__ cT) {
  __shared__ float gbuf[4][4][BB][17];   // [gate][kw][b][j] (+1 pad word vs 16)
  const int tid = threadIdx.x;
  const int wave = tid >> 6, lane = tid & 63;
  const int g = wave & 3, kw = wave >> 2;
  const int lr = lane & 15, lk = (lane >> 4) * 8;
  const int j0 = blockIdx.x * 16;

  floatx4 acc[5] = {};
  const bf16* brow = Whh + (long long)(g * H + j0 + lr) * HP + lk + kw * 32;
  const bf16* arow = hprev + (long long)lr * HP + lk + kw * 32;
  constexpr int NI = HP / 128;
#pragma unroll
  for (int ki = 0; ki < NI; ++ki) {
    bf16x8 bfrag = *(const bf16x8*)(brow + ki * 128);
#pragma unroll
    for (int mi = 0; mi < 5; ++mi) {
      bf16x8 afrag = *(const bf16x8*)(arow + mi * 16 * HP + ki * 128);
      acc[mi] = __builtin_amdgcn_mfma_f32_16x16x32_bf16(afrag, bfrag, acc[mi], 0, 0, 0);
    }
  }
  const int rb = (lane >> 4) * 4;
#pragma unroll
  for (int mi = 0; mi < 5; ++mi)
#pragma unroll
    for (int i = 0; i < 4; ++i)
      gbuf[g][kw][mi * 16 + rb + i][lr] = acc[mi][i];
  __syncthreads();

  for (int p = tid; p < BB * 16; p += 1024) {
    int b = p >> 4, j = p & 15;
    int jc = j0 + j;
    if (jc < H) {
      float iv = 0.f, fv = 0.f, gv = 0.f, ov = 0.f;
#pragma unroll
      for (int q = 0; q < 4; ++q) {
        iv += gbuf[0][q][b][j];
        fv += gbuf[1][q][b][j];
        gv += gbuf[2][q][b][j];
        ov += gbuf[3][q][b][j];
      }
      const float* xr = xWt + (long long)b * ldxw + jc;
      iv += xr[0 * H];
      fv += xr[1 * H];
      gv += xr[2 * H];
      ov += xr[3 * H];
      float cp = c[b * HP + jc];
      float ig = 1.f / (1.f + __expf(-iv));
      float fg = 1.f / (1.f + __expf(-fv));
      float og = 1.f / (1.f + __expf(-ov));
      float cn = fg * cp + ig * tanhf(gv);
      float hn = og * tanhf(cn);
      c[b * HP + jc] = cn;
      yt[b * HP + jc] = __float2bfloat16(hn);
      if (hT) { hT[b * H + jc] = hn; cT[b * H + jc] = cn; }
    } else {
      yt[b * HP + jc] = __float2bfloat16(0.f);
    }
  }
}

// ---------------- host launch ----------------
extern "C" void kernel_launch(void* const* d_in, const int* in_sizes, int n_in,
                              void* d_out, int out_size, void* d_ws, size_t ws_size,
                              hipStream_t stream) {
  const int*   tokens = (const int*)d_in[0];
  const float* embW   = (const float*)d_in[1];
  const float* decW   = (const float*)d_in[2];
  const float* decb   = (const float*)d_in[3];
  const float* Wih[3] = {(const float*)d_in[4],  (const float*)d_in[10], (const float*)d_in[16]};
  const float* Whh[3] = {(const float*)d_in[5],  (const float*)d_in[11], (const float*)d_in[17]};
  const float* bih[3] = {(const float*)d_in[6],  (const float*)d_in[12], (const float*)d_in[18]};
  const float* bhh[3] = {(const float*)d_in[7],  (const float*)d_in[13], (const float*)d_in[19]};
  const float* h0[3]  = {(const float*)d_in[8],  (const float*)d_in[14], (const float*)d_in[20]};
  const float* c0[3]  = {(const float*)d_in[9],  (const float*)d_in[15], (const float*)d_in[21]};

  // ---- workspace layout (bump allocator, 256B aligned) ----
  size_t off = 0;
  auto alloc = [&](size_t bytes) {
    void* p = (char*)d_ws + off;
    off += (bytes + 255) & ~(size_t)255;
    return p;
  };
  bf16* Wih0b = (bf16*)alloc((size_t)G1P * EP  * 2);
  bf16* Whh0b = (bf16*)alloc((size_t)G1P * HP1 * 2);
  bf16* Wih1b = (bf16*)alloc((size_t)G1P * HP1 * 2);
  bf16* Whh1b = (bf16*)alloc((size_t)G1P * HP1 * 2);
  bf16* Wih2b = (bf16*)alloc((size_t)G2P * HP1 * 2);
  bf16* Whh2b = (bf16*)alloc((size_t)G2  * HP2 * 2);
  bf16* decWb = (bf16*)alloc((size_t)VP  * EP  * 2);
  bf16* x0    = (bf16*)alloc((size_t)TBP * EP  * 2);
  bf16* y0    = (bf16*)alloc((size_t)TBP * HP1 * 2);
  bf16* y1    = (bf16*)alloc((size_t)TBP * HP1 * 2);
  bf16* y2    = (bf16*)alloc((size_t)TBP * HP2 * 2);
  float* xW   = (float*)alloc((size_t)TBP * G1P * 4);
  bf16* hini[3]; float* cbuf[3];
  int Harr[3]  = {H1, H1, H2r};
  int Hparr[3] = {HP1, HP1, HP2};
  for (int l = 0; l < 3; ++l) {
    hini[l] = (bf16*)alloc((size_t)BB * Hparr[l] * 2);
    cbuf[l] = (float*)alloc((size_t)BB * Hparr[l] * 4);
  }

  auto cvt = [&](const float* s, bf16* d, int N, int K, int Np, int Kp) {
    long long tot = (long long)Np * Kp;
    conv_pad<<<dim3((unsigned)((tot + 255) / 256)), dim3(256), 0, stream>>>(s, d, N, K, Np, Kp);
  };
  // weights -> bf16 (zero-padded)
  cvt(Wih[0], Wih0b, G1, EE,  G1P, EP);
  cvt(Whh[0], Whh0b, G1, H1,  G1P, HP1);
  cvt(Wih[1], Wih1b, G1, H1,  G1P, HP1);
  cvt(Whh[1], Whh1b, G1, H1,  G1P, HP1);
  cvt(Wih[2], Wih2b, G2, H1,  G2P, HP1);
  cvt(Whh[2], Whh2b, G2, H2r, G2,  HP2);
  cvt(decW,   decWb, VV, EE,  VP,  EP);
  // initial states
  for (int l = 0; l < 3; ++l) {
    cvt(h0[l], hini[l], BB, Harr[l], BB, Hparr[l]);
    int n = BB * Hparr[l];
    cinit<<<dim3((n + 255) / 256), dim3(256), 0, stream>>>(c0[l], cbuf[l], Harr[l], Hparr[l]);
  }
  // y2: layer-2 steps only write cols < 400; clear whole buffer once so pad
  // cols [400,512) are guaranteed zero for the lstm hprev reads (K=512).
  {
    long long n16 = (long long)TBP * HP2 * 2 / 16;
    zfill16<<<dim3((unsigned)((n16 + 255) / 256)), dim3(256), 0, stream>>>(y2, n16);
  }
  // embedding
  emb_gather<<<dim3(TB), dim3(128), 0, stream>>>(tokens, embW, x0);

  auto gemm = [&](const bf16* A, int lda, const bf16* B, int ldb, float* C, long long ldc,
                  int M, int N, int K, const float* b1, const float* b2, int ntc) {
    dim3 grid((N + 127) / 128, (M + 127) / 128);
    gemm_bf16_nt<<<grid, dim3(256), 0, stream>>>(A, lda, B, ldb, C, ldc, M, N, K, b1, b2, ntc);
  };

  // output offsets
  float* dec_out = (float*)d_out;
  float* hT0 = dec_out + (size_t)TB * VV;
  float* cT0 = hT0 + (size_t)BB * H1;
  float* hT1 = cT0 + (size_t)BB * H1;
  float* cT1 = hT1 + (size_t)BB * H1;
  float* hT2 = cT1 + (size_t)BB * H1;
  float* cT2 = hT2 + (size_t)BB * H2r;

  const bf16* xin[3]  = {x0, y0, y1};
  int kin[3]          = {EP, HP1, HP1};
  const bf16* Wihb[3] = {Wih0b, Wih1b, Wih2b};
  const bf16* Whhb[3] = {Whh0b, Whh1b, Whh2b};
  bf16* yout[3]       = {y0, y1, y2};
  int Gr[3]           = {G1, G1, G2};
  float* hTo[3]       = {hT0, hT1, hT2};
  float* cTo[3]       = {cT0, cT1, cT2};

  for (int l = 0; l < 3; ++l) {
    int H = Harr[l], Hp = Hparr[l];
    // xW = x_l * Wih^T + bih + bhh   [TB, 4H] in a [TBP, G1P] buffer
    gemm(xin[l], kin[l], Wihb[l], kin[l], xW, G1P, TB, Gr[l], kin[l], bih[l], bhh[l], 0);
    int nblk = (H + 15) / 16;   // 72 for H=1150, 25 for H=400
    for (int t = 0; t < TT; ++t) {
      const bf16* hp = (t == 0) ? hini[l] : (yout[l] + (size_t)(t - 1) * BB * Hp);
      bf16* yt = yout[l] + (size_t)t * BB * Hp;
      const float* xWt = xW + (size_t)t * BB * G1P;
      bool last = (t == TT - 1);
      if (l < 2)
        lstm_step<HP1><<<dim3(nblk), dim3(1024), 0, stream>>>(
            hp, Whhb[l], xWt, G1P, cbuf[l], yt, H,
            last ? hTo[l] : nullptr, last ? cTo[l] : nullptr);
      else
        lstm_step<HP2><<<dim3(nblk), dim3(1024), 0, stream>>>(
            hp, Whhb[l], xWt, G1P, cbuf[l], yt, H,
            last ? hTo[l] : nullptr, last ? cTo[l] : nullptr);
    }
  }

  // decoder: d_out[TB, V] = y2 * decW^T + dec_b   (non-temporal C stores)
  gemm(y2, HP2, decWb, EP, dec_out, VV, TB, VV, EP, decb, nullptr, 1);
}